// Round 7
// baseline (500.657 us; speedup 1.0000x reference)
//
#include <hip/hip_runtime.h>

// StrokeField R7: exact stroke culling + coord-carrying two-level sort.
// R6 post-mortem: kF bound by 133MB gather (cw[idx]) + 151MB scattered
// writes; sort pipeline ~210us (kD only 64 blocks, kC re-reads cw).
// R7: records carry coords through the sort (kF reads coalesced float4),
// kD parallelized to 256 blocks via device-atomic cell cursors (point order
// within a cell cannot affect results - each point's blend is independent).

#define NC_DIM 16
#define NC 4096
#define MAXS 512
#define CELL_INV 8.0f

typedef unsigned short u16;
typedef unsigned int u32;
typedef unsigned long long u64;

__device__ __forceinline__ void contract_pt(float x, float y, float z,
                                            float& cx, float& cy, float& cz) {
    float n2 = fmaf(x, x, fmaf(y, y, z * z));
    float nn = fmaxf(__builtin_amdgcn_sqrtf(n2), 1e-9f);
    float invn = 1.0f / nn;
    float scl = (nn <= 1.0f) ? 0.5f : (2.0f - invn) * (0.5f * invn);
    cx = x * scl; cy = y * scl; cz = z * scl;
}
__device__ __forceinline__ int cid_of(float cx, float cy, float cz) {
    int ix = (int)floorf((cx + 1.0f) * CELL_INV);
    int iy = (int)floorf((cy + 1.0f) * CELL_INV);
    int iz = (int)floorf((cz + 1.0f) * CELL_INV);
    ix = min(max(ix, 0), 15); iy = min(max(iy, 0), 15); iz = min(max(iz, 0), 15);
    return ix | (iy << 4) | (iz << 8);
}
__device__ __forceinline__ int sid_of(int cid) {
    return ((cid >> 2) & 3) | (((cid >> 6) & 3) << 2) | (((cid >> 10) & 3) << 4);
}
__device__ __forceinline__ int sub_of(int cid) {
    return (cid & 3) | (((cid >> 4) & 3) << 2) | (((cid >> 8) & 3) << 4);
}
__device__ __forceinline__ int cid_from(int s, int t) {
    int ix = ((s & 3) << 2) | (t & 3);
    int iy = (((s >> 2) & 3) << 2) | ((t >> 2) & 3);
    int iz = (((s >> 4) & 3) << 2) | ((t >> 4) & 3);
    return ix | (iy << 4) | (iz << 8);
}

// kA: contract, write cw, per-cell histogram.
__global__ __launch_bounds__(256) void kA(
    const float* __restrict__ coords, float* __restrict__ out,
    int* __restrict__ cnt, int n)
{
    int base = blockIdx.x * 1024 + threadIdx.x;
    float* cw = out + 4 * (size_t)n;
#pragma unroll
    for (int k = 0; k < 4; ++k) {
        int i = base + k * 256;
        if (i < n) {
            float cx, cy, cz;
            contract_pt(coords[3 * i], coords[3 * i + 1], coords[3 * i + 2], cx, cy, cz);
            cw[3 * i] = cx; cw[3 * i + 1] = cy; cw[3 * i + 2] = cz;
            atomicAdd(&cnt[cid_of(cx, cy, cz)], 1);
        }
    }
}

// kB: single-block scan over 4096 cells in (supercell, subcell) order ->
// cellCursor (slot bases, 64-aligned), supercell bases/cursors, chunkInfo.
__global__ __launch_bounds__(1024) void kB(
    const int* __restrict__ cnt, int* __restrict__ cellCursor,
    int* __restrict__ superBase, int* __restrict__ superCursor,
    int2* __restrict__ chunkInfo)
{
    __shared__ int waveSums[16];
    int t = threadIdx.x;
    int ch[4], cds[4], tot = 0;
#pragma unroll
    for (int j = 0; j < 4; ++j) {
        int k = 4 * t + j;
        cds[j] = cid_from(k >> 6, k & 63);
        ch[j] = (cnt[cds[j]] + 63) >> 6;
        tot += ch[j];
    }
    int lane = t & 63, wid = t >> 6;
    int v = tot;
    for (int off = 1; off < 64; off <<= 1) {
        int u = __shfl_up(v, off, 64);
        if (lane >= off) v += u;
    }
    if (lane == 63) waveSums[wid] = v;
    __syncthreads();
    if (wid == 0) {
        int wv = (lane < 16) ? waveSums[lane] : 0;
        for (int off = 1; off < 16; off <<= 1) {
            int u = __shfl_up(wv, off, 64);
            if (lane >= off) wv += u;
        }
        if (lane < 16) waveSums[lane] = wv;
    }
    __syncthreads();
    int waveOff = (wid == 0) ? 0 : waveSums[wid - 1];
    int running = waveOff + v - tot;           // exclusive chunk prefix
#pragma unroll
    for (int j = 0; j < 4; ++j) {
        int k = 4 * t + j;
        int slotBase = running << 6;
        cellCursor[cds[j]] = slotBase;
        if ((k & 63) == 0) { superBase[k >> 6] = slotBase; superCursor[k >> 6] = slotBase; }
        for (int q = 0; q < ch[j]; ++q)
            chunkInfo[running + q] = make_int2(cds[j], slotBase + (q << 6));
        running += ch[j];
    }
}

// kC: block-aggregated scatter of packed (idx | sub<<26) into supercell tmp.
__global__ __launch_bounds__(256) void kC(
    const float* __restrict__ out, int* __restrict__ superCursor,
    u32* __restrict__ tmp, int n)
{
    __shared__ int scnt[64], sbase[64];
    if (threadIdx.x < 64) scnt[threadIdx.x] = 0;
    __syncthreads();
    const float* cw = out + 4 * (size_t)n;
    int base = blockIdx.x * 2048 + threadIdx.x;
    int sid[8]; u32 rec[8];
#pragma unroll
    for (int k = 0; k < 8; ++k) {
        int i = base + k * 256;
        if (i < n) {
            int c = cid_of(cw[3 * i], cw[3 * i + 1], cw[3 * i + 2]);
            sid[k] = sid_of(c);
            rec[k] = (u32)i | ((u32)sub_of(c) << 26);
            atomicAdd(&scnt[sid[k]], 1);
        } else sid[k] = -1;
    }
    __syncthreads();
    if (threadIdx.x < 64) {
        int c = scnt[threadIdx.x];
        sbase[threadIdx.x] = c ? atomicAdd(&superCursor[threadIdx.x], c) : 0;
        scnt[threadIdx.x] = 0;
    }
    __syncthreads();
#pragma unroll
    for (int k = 0; k < 8; ++k) {
        if (sid[k] >= 0) {
            int r = atomicAdd(&scnt[sid[k]], 1);
            tmp[sbase[sid[k]] + r] = rec[k];
        }
    }
}

// kD (pack): 4 blocks per supercell; counting sort into cell runs, emitting
// float4(cx,cy,cz,idx) records (gathers cw here, L3-backed).
__global__ __launch_bounds__(256) void kD_pack(
    const int* __restrict__ superBase, const int* __restrict__ superCursor,
    const u32* __restrict__ tmp, const float* __restrict__ out,
    float4* __restrict__ sortedF, int* __restrict__ cellCursor, int n)
{
    __shared__ int h[64], gbase[64], curLoc[64];
    int s = blockIdx.x >> 2, q = blockIdx.x & 3;
    int t = threadIdx.x;
    if (t < 64) h[t] = 0;
    __syncthreads();
    int base = superBase[s];
    int cntS = superCursor[s] - base;
    int j0 = (cntS * q) >> 2, j1 = (cntS * (q + 1)) >> 2;
    for (int j = j0 + t; j < j1; j += 256)
        atomicAdd(&h[tmp[base + j] >> 26], 1);
    __syncthreads();
    if (t < 64) {
        gbase[t] = h[t] ? atomicAdd(&cellCursor[cid_from(s, t)], h[t]) : 0;
        curLoc[t] = 0;
    }
    __syncthreads();
    const float* cw = out + 4 * (size_t)n;
    for (int j = j0 + t; j < j1; j += 256) {
        u32 rec = tmp[base + j];
        int sub = rec >> 26;
        int idx = rec & 0x3FFFFFF;
        int r = atomicAdd(&curLoc[sub], 1);
        sortedF[gbase[sub] + r] = make_float4(
            cw[3 * idx], cw[3 * idx + 1], cw[3 * idx + 2], __int_as_float(idx));
    }
}

// kD (idx-only): same, but writes 4B indices (kF gathers cw).
__global__ __launch_bounds__(256) void kD_idx(
    const int* __restrict__ superBase, const int* __restrict__ superCursor,
    const u32* __restrict__ tmp,
    int* __restrict__ sortedI, int* __restrict__ cellCursor)
{
    __shared__ int h[64], gbase[64], curLoc[64];
    int s = blockIdx.x >> 2, q = blockIdx.x & 3;
    int t = threadIdx.x;
    if (t < 64) h[t] = 0;
    __syncthreads();
    int base = superBase[s];
    int cntS = superCursor[s] - base;
    int j0 = (cntS * q) >> 2, j1 = (cntS * (q + 1)) >> 2;
    for (int j = j0 + t; j < j1; j += 256)
        atomicAdd(&h[tmp[base + j] >> 26], 1);
    __syncthreads();
    if (t < 64) {
        gbase[t] = h[t] ? atomicAdd(&cellCursor[cid_from(s, t)], h[t]) : 0;
        curLoc[t] = 0;
    }
    __syncthreads();
    for (int j = j0 + t; j < j1; j += 256) {
        u32 rec = tmp[base + j];
        int sub = rec >> 26;
        int r = atomicAdd(&curLoc[sub], 1);
        sortedI[gbase[sub] + r] = (int)(rec & 0x3FFFFFF);
    }
}

// kE: per-cell ordered stroke sublist (AABB vs sphere, exact-zero margin).
__global__ __launch_bounds__(256) void kE(
    const float* __restrict__ shape, u16* __restrict__ cellList,
    int* __restrict__ strokeCnt, int ns)
{
    int wave = (blockIdx.x * blockDim.x + threadIdx.x) >> 6;
    int lane = threadIdx.x & 63;
    if (wave >= NC) return;
    int ix = wave & 15, iy = (wave >> 4) & 15, iz = wave >> 8;
    float lox = -1.0f + ix * 0.125f, hix = lox + 0.125f;
    float loy = -1.0f + iy * 0.125f, hiy = loy + 0.125f;
    float loz = -1.0f + iz * 0.125f, hiz = loz + 0.125f;
    int cnt = 0;
    u16* lst = cellList + (size_t)wave * MAXS;
    for (int base = 0; base < ns; base += 64) {
        int s = base + lane;
        bool pass = false;
        if (s < ns) {
            float4 sp = ((const float4*)shape)[s];
            float dx = sp.x - fminf(fmaxf(sp.x, lox), hix);
            float dy = sp.y - fminf(fmaxf(sp.y, loy), hiy);
            float dz = sp.z - fminf(fmaxf(sp.z, loz), hiz);
            float d2 = fmaf(dx, dx, fmaf(dy, dy, dz * dz));
            float rr = sp.w + 0.101f;
            pass = d2 <= rr * rr;
        }
        u64 m = __ballot(pass);
        if (pass) lst[cnt + __popcll(m & ((1ull << lane) - 1ull))] = (u16)s;
        cnt += __popcll(m);
    }
    if (lane == 0) strokeCnt[wave] = cnt;
}

// Blend inner loop (R5/R6-verified): wave-uniform broadcast of stroke ids.
#define BLEND_LOOP(CX, CY, CZ)                                                  \
    float T = 1.0f, Ad = 0.0f, Ar = 0.0f, Ag = 0.0f, Ab = 0.0f;                 \
    for (int jb = (((nl + 63) >> 6) << 6) - 64; jb >= 0; jb -= 64) {            \
        int jl = jb + lane;                                                     \
        int myId = (jl < nl) ? (int)lst[jl] : 0;                                \
        int hi = nl - jb; hi = hi > 64 ? 64 : hi;                               \
        int sid = __builtin_amdgcn_readlane(myId, hi - 1);                      \
        float4 a = sA[sid];                                                     \
        float4 b = sB[sid];                                                     \
        for (int jj = hi - 1; jj >= 0; --jj) {                                  \
            int sidn = __builtin_amdgcn_readlane(myId, jj > 0 ? jj - 1 : 0);    \
            float4 an = sA[sidn];                                               \
            float4 bn = sB[sidn];                                               \
            float dx = (CX) - a.x, dy = (CY) - a.y, dz = (CZ) - a.z;            \
            float d2 = fmaf(dx, dx, fmaf(dy, dy, dz * dz));                     \
            float dist = __builtin_amdgcn_sqrtf(d2);                            \
            float omt = fminf(fmaxf(fmaf(5.0f, dist, a.w), 0.0f), 1.0f);        \
            float Tn = omt * T;                                                 \
            float tT = T - Tn;                                                  \
            Ad = fmaf(tT, b.x, Ad);                                             \
            Ar = fmaf(tT, b.y, Ar);                                             \
            Ag = fmaf(tT, b.z, Ag);                                             \
            Ab = fmaf(tT, b.w, Ab);                                             \
            T = Tn;                                                             \
            a = an; b = bn;                                                     \
        }                                                                       \
    }

#define STAGE_STROKES()                                                         \
    __shared__ float4 sA[MAXS];                                                 \
    __shared__ float4 sB[MAXS];                                                 \
    for (int s = threadIdx.x; s < ns; s += blockDim.x) {                        \
        float4 sp = ((const float4*)shape)[s];                                  \
        sA[s] = make_float4(sp.x, sp.y, sp.z, fmaf(-5.0f, sp.w, 0.5f));         \
        sB[s] = make_float4(fmaxf(alpha[s], 0.0f) * 50.0f,                      \
                            color[3 * s], color[3 * s + 1], color[3 * s + 2]);  \
    }                                                                           \
    __syncthreads();

#define STORE_RESULT(IDX)                                                       \
    if ((IDX) >= 0) {                                                           \
        float inv = 1.0f / (1.0f + 1e-6f - T);                                  \
        out[(IDX)] = Ad;                                                        \
        float* rgb = out + n;                                                   \
        rgb[3 * (IDX)]     = fminf(fmaxf(Ar * inv, 0.0f), 1.0f);                \
        rgb[3 * (IDX) + 1] = fminf(fmaxf(Ag * inv, 0.0f), 1.0f);                \
        rgb[3 * (IDX) + 2] = fminf(fmaxf(Ab * inv, 0.0f), 1.0f);                \
    }

__global__ __launch_bounds__(256) void kF_pack(
    const float* __restrict__ shape, const float* __restrict__ color,
    const float* __restrict__ alpha,
    const int2* __restrict__ chunkInfo, const float4* __restrict__ sortedF,
    const u16* __restrict__ cellList, const int* __restrict__ strokeCnt,
    float* __restrict__ out, int n, int ns, int maxChunks)
{
    if (chunkInfo[blockIdx.x * 4].x < 0) return;   // dense fill -> whole block idle
    STAGE_STROKES();
    int k = blockIdx.x * 4 + (threadIdx.x >> 6);
    int lane = threadIdx.x & 63;
    if (k >= maxChunks) return;
    int2 info = chunkInfo[k];
    if (info.x < 0) return;
    float4 rec = sortedF[info.y + lane];           // pads: 0xFF -> idx<0
    int idx = __float_as_int(rec.w);
    int nl = strokeCnt[info.x];
    const u16* lst = cellList + (size_t)info.x * MAXS;
    BLEND_LOOP(rec.x, rec.y, rec.z)
    STORE_RESULT(idx)
}

__global__ __launch_bounds__(256) void kF_idx(
    const float* __restrict__ shape, const float* __restrict__ color,
    const float* __restrict__ alpha,
    const int2* __restrict__ chunkInfo, const int* __restrict__ sortedI,
    const u16* __restrict__ cellList, const int* __restrict__ strokeCnt,
    float* __restrict__ out, int n, int ns, int maxChunks)
{
    if (chunkInfo[blockIdx.x * 4].x < 0) return;
    STAGE_STROKES();
    int k = blockIdx.x * 4 + (threadIdx.x >> 6);
    int lane = threadIdx.x & 63;
    if (k >= maxChunks) return;
    int2 info = chunkInfo[k];
    if (info.x < 0) return;
    int idx = sortedI[info.y + lane];
    const float* cw = out + 4 * (size_t)n;
    float cx = 1e9f, cy = 1e9f, cz = 1e9f;
    if (idx >= 0) { cx = cw[3 * idx]; cy = cw[3 * idx + 1]; cz = cw[3 * idx + 2]; }
    int nl = strokeCnt[info.x];
    const u16* lst = cellList + (size_t)info.x * MAXS;
    BLEND_LOOP(cx, cy, cz)
    STORE_RESULT(idx)
}

// ---- Fallback: R4 direct kernel ----
#define PTS 4
__global__ __launch_bounds__(256) void stroke_direct(
    const float* __restrict__ coords, const float* __restrict__ shape,
    const float* __restrict__ color, const float* __restrict__ alpha,
    float* __restrict__ out, int n, int ns)
{
    __shared__ float4 fA[MAXS + 1];
    __shared__ float4 fB[MAXS + 1];
    for (int s = threadIdx.x; s < ns; s += blockDim.x) {
        float4 sp = ((const float4*)shape)[s];
        fA[s + 1] = make_float4(sp.x, sp.y, sp.z, fmaf(-5.0f, sp.w, 0.5f));
        fB[s + 1] = make_float4(fmaxf(alpha[s], 0.0f) * 50.0f,
                                color[3 * s], color[3 * s + 1], color[3 * s + 2]);
    }
    __syncthreads();
    const int base = blockIdx.x * (blockDim.x * PTS) + threadIdx.x;
    float cx[PTS], cy[PTS], cz[PTS], T[PTS], Ad[PTS], Ar[PTS], Ag[PTS], Ab[PTS];
#pragma unroll
    for (int k = 0; k < PTS; ++k) {
        int i = base + k * 256; i = (i < n) ? i : (n - 1);
        contract_pt(coords[3 * i], coords[3 * i + 1], coords[3 * i + 2],
                    cx[k], cy[k], cz[k]);
        T[k] = 1.0f; Ad[k] = Ar[k] = Ag[k] = Ab[k] = 0.0f;
    }
    float4 a = fA[ns], b = fB[ns];
#pragma unroll 2
    for (int s = ns - 1; s >= 0; --s) {
        float4 an = fA[s], bn = fB[s];
#pragma unroll
        for (int k = 0; k < PTS; ++k) {
            float dx = cx[k] - a.x, dy = cy[k] - a.y, dz = cz[k] - a.z;
            float d2 = fmaf(dx, dx, fmaf(dy, dy, dz * dz));
            float dist = __builtin_amdgcn_sqrtf(d2);
            float omt = fminf(fmaxf(fmaf(5.0f, dist, a.w), 0.0f), 1.0f);
            float Tn = omt * T[k];
            float tT = T[k] - Tn;
            Ad[k] = fmaf(tT, b.x, Ad[k]); Ar[k] = fmaf(tT, b.y, Ar[k]);
            Ag[k] = fmaf(tT, b.z, Ag[k]); Ab[k] = fmaf(tT, b.w, Ab[k]);
            T[k] = Tn;
        }
        a = an; b = bn;
    }
    float* rgb = out + n;
    float* cw  = out + 4 * (size_t)n;
#pragma unroll
    for (int k = 0; k < PTS; ++k) {
        int i = base + k * 256;
        if (i >= n) break;
        float inv = 1.0f / (1.0f + 1e-6f - T[k]);
        out[i] = Ad[k];
        rgb[3 * i]     = fminf(fmaxf(Ar[k] * inv, 0.0f), 1.0f);
        rgb[3 * i + 1] = fminf(fmaxf(Ag[k] * inv, 0.0f), 1.0f);
        rgb[3 * i + 2] = fminf(fmaxf(Ab[k] * inv, 0.0f), 1.0f);
        cw[3 * i]     = cx[k];
        cw[3 * i + 1] = cy[k];
        cw[3 * i + 2] = cz[k];
    }
}

extern "C" void kernel_launch(void* const* d_in, const int* in_sizes, int n_in,
                              void* d_out, int out_size, void* d_ws, size_t ws_size,
                              hipStream_t stream) {
    const float* coords = (const float*)d_in[0];
    const float* shape  = (const float*)d_in[1];
    const float* color  = (const float*)d_in[2];
    const float* alpha  = (const float*)d_in[3];
    float* out = (float*)d_out;

    int n  = in_sizes[0] / 3;
    int ns = in_sizes[1] / 4;

    auto al = [](size_t v) { return (v + 255) & ~(size_t)255; };
    int maxChunks = (n + 63) / 64 + NC;
    size_t nslots = (size_t)maxChunks * 64;
    size_t o_cnt    = 0;                                  // 16KB
    size_t o_cur    = 16384;                              // cellCursor 16KB
    size_t o_sup    = 32768;                              // superBase+Cursor 512B
    size_t o_chunk  = al(o_sup + 512);
    size_t o_list   = al(o_chunk + (size_t)maxChunks * 8);
    size_t o_scnt   = o_list + (size_t)NC * MAXS * 2;
    size_t o_tmp    = al(o_scnt + NC * 4);
    size_t o_sorted = al(o_tmp + nslots * 4);
    size_t needB    = o_sorted + nslots * 4;
    size_t needA    = o_sorted + nslots * 16;

    bool ok = (ns <= MAXS) && (n >= 1) && (n < (1 << 26));
    if (ok && ws_size >= needB) {
        char* w = (char*)d_ws;
        int*  cnt        = (int*)(w + o_cnt);
        int*  cellCursor = (int*)(w + o_cur);
        int*  superBase  = (int*)(w + o_sup);
        int*  superCur   = (int*)(w + o_sup + 256);
        int2* chunkInfo  = (int2*)(w + o_chunk);
        u16*  cellList   = (u16*)(w + o_list);
        int*  strokeCnt  = (int*)(w + o_scnt);
        u32*  tmp        = (u32*)(w + o_tmp);
        bool  pack       = ws_size >= needA;

        hipMemsetAsync(cnt, 0, NC * 4, stream);
        hipMemsetAsync(chunkInfo, 0xFF, (size_t)maxChunks * 8, stream);
        hipMemsetAsync(w + o_sorted, 0xFF, nslots * (pack ? 16 : 4), stream);

        kA<<<(n + 1023) / 1024, 256, 0, stream>>>(coords, out, cnt, n);
        kB<<<1, 1024, 0, stream>>>(cnt, cellCursor, superBase, superCur, chunkInfo);
        kC<<<(n + 2047) / 2048, 256, 0, stream>>>(out, superCur, tmp, n);
        kE<<<(NC * 64) / 256, 256, 0, stream>>>(shape, cellList, strokeCnt, ns);
        if (pack) {
            float4* sortedF = (float4*)(w + o_sorted);
            kD_pack<<<256, 256, 0, stream>>>(superBase, superCur, tmp, out,
                                             sortedF, cellCursor, n);
            kF_pack<<<(maxChunks + 3) / 4, 256, 0, stream>>>(
                shape, color, alpha, chunkInfo, sortedF, cellList, strokeCnt,
                out, n, ns, maxChunks);
        } else {
            int* sortedI = (int*)(w + o_sorted);
            kD_idx<<<256, 256, 0, stream>>>(superBase, superCur, tmp,
                                            sortedI, cellCursor);
            kF_idx<<<(maxChunks + 3) / 4, 256, 0, stream>>>(
                shape, color, alpha, chunkInfo, sortedI, cellList, strokeCnt,
                out, n, ns, maxChunks);
        }
    } else {
        int per_block = 256 * PTS;
        int grid = (n + per_block - 1) / per_block;
        stroke_direct<<<grid, 256, 0, stream>>>(coords, shape, color, alpha, out, n, ns);
    }
}